// Round 1
// baseline (139.897 us; speedup 1.0000x reference)
//
#include <hip/hip_runtime.h>
#include <hip/hip_bf16.h>

// RewardCLIP loss:
//   pos[i] = dot(input_embs[i], image_embs[i])
//   neg[i] = dot(neg_input_embs[i], image_embs[i])
//   loss = -mean(log_sigmoid((pos - neg) * alpha))
// Fused: diff[i] = dot(input_embs[i] - neg_input_embs[i], image_embs[i])
//
// Memory-bound: 3 x 65536 x 1024 x 4B = 768 MiB read. Wave-per-row,
// float4 coalesced loads, shuffle reduce, block partials -> d_ws,
// single-block finalize.

#define DIMS 1024
#define BLOCKS 2048
#define THREADS 256
#define WAVES_PER_BLOCK (THREADS / 64)

__global__ __launch_bounds__(THREADS) void rewardclip_main(
    const float* __restrict__ a,      // input_embs
    const float* __restrict__ b,      // neg_input_embs
    const float* __restrict__ c,      // image_embs
    const int* __restrict__ alpha_p,  // scalar (python int)
    int rows,
    float* __restrict__ partials) {
  const int tid  = threadIdx.x;
  const int lane = tid & 63;
  const int wave = tid >> 6;
  const int gwave  = blockIdx.x * WAVES_PER_BLOCK + wave;
  const int nwaves = gridDim.x * WAVES_PER_BLOCK;

  const float alpha = (float)(*alpha_p);

  float acc = 0.0f;  // per-(wave,lane) accumulator of log_sigmoid values (valid in lane 0)

  for (int row = gwave; row < rows; row += nwaves) {
    const float4* __restrict__ pa = (const float4*)(a + (size_t)row * DIMS);
    const float4* __restrict__ pb = (const float4*)(b + (size_t)row * DIMS);
    const float4* __restrict__ pc = (const float4*)(c + (size_t)row * DIMS);

    float d = 0.0f;
#pragma unroll
    for (int j = 0; j < DIMS / (64 * 4); ++j) {   // 4 iterations
      const int idx = j * 64 + lane;              // float4 index; lanes contiguous
      const float4 va = pa[idx];
      const float4 vb = pb[idx];
      const float4 vc = pc[idx];
      d += (va.x - vb.x) * vc.x;
      d += (va.y - vb.y) * vc.y;
      d += (va.z - vb.z) * vc.z;
      d += (va.w - vb.w) * vc.w;
    }

    // 64-lane shuffle reduction
#pragma unroll
    for (int off = 32; off > 0; off >>= 1) d += __shfl_down(d, off, 64);

    if (lane == 0) {
      const float x = d * alpha;
      // numerically stable log_sigmoid
      const float ls = fminf(x, 0.0f) - log1pf(__expf(-fabsf(x)));
      acc += ls;
    }
  }

  __shared__ float s[WAVES_PER_BLOCK];
  if (lane == 0) s[wave] = acc;
  __syncthreads();
  if (tid == 0) {
    float t = 0.0f;
#pragma unroll
    for (int w = 0; w < WAVES_PER_BLOCK; ++w) t += s[w];
    partials[blockIdx.x] = t;  // fully overwritten every launch: deterministic
  }
}

__global__ __launch_bounds__(THREADS) void rewardclip_finalize(
    const float* __restrict__ partials, int nparts, int rows,
    float* __restrict__ out) {
  const int tid  = threadIdx.x;
  const int lane = tid & 63;
  const int wave = tid >> 6;

  float s = 0.0f;
  for (int i = tid; i < nparts; i += THREADS) s += partials[i];

#pragma unroll
  for (int off = 32; off > 0; off >>= 1) s += __shfl_down(s, off, 64);

  __shared__ float ws[WAVES_PER_BLOCK];
  if (lane == 0) ws[wave] = s;
  __syncthreads();
  if (tid == 0) {
    float t = 0.0f;
#pragma unroll
    for (int w = 0; w < WAVES_PER_BLOCK; ++w) t += ws[w];
    out[0] = -t / (float)rows;
  }
}

extern "C" void kernel_launch(void* const* d_in, const int* in_sizes, int n_in,
                              void* d_out, int out_size, void* d_ws, size_t ws_size,
                              hipStream_t stream) {
  const float* a = (const float*)d_in[0];       // input_embs
  const float* b = (const float*)d_in[1];       // neg_input_embs
  const float* c = (const float*)d_in[2];       // image_embs
  const int* alpha_p = (const int*)d_in[3];     // python int scalar

  const int rows = in_sizes[0] / DIMS;          // 65536
  float* partials = (float*)d_ws;               // BLOCKS floats
  float* out = (float*)d_out;

  rewardclip_main<<<BLOCKS, THREADS, 0, stream>>>(a, b, c, alpha_p, rows, partials);
  rewardclip_finalize<<<1, THREADS, 0, stream>>>(partials, BLOCKS, rows, out);
}